// Round 3
// baseline (453.384 us; speedup 1.0000x reference)
//
#include <hip/hip_runtime.h>

// Encoder: 4-layer MLP (3->16->32->64->128) + mean-pool over 2M points.
// Layer 4 is linear and mean is linear => apply W4/b4 AFTER pooling.
// Per-point work: L1+L2+L3 ~ 2944 VALU inst; f32-VALU roofline ~75 us.
//
// Round-2 lesson: __launch_bounds__(256,2) sets waves-per-eu RANGE [2,8];
// the allocator chases the max (8) and spills acc[64]+h2[32] to AGPRs
// (VGPR_Count=96, VALUBusy 65% but 3.2x the useful inst count = accvgpr
// spill moves). Pin the range EXACTLY with amdgpu_waves_per_eu(2,2) so
// the budget is 256 VGPRs and the ~130-reg live set stays resident.

#define GRID1 512   // 2 blocks/CU x 256 CUs (2 waves/SIMD)

__global__ __launch_bounds__(256)
__attribute__((amdgpu_waves_per_eu(2, 2)))
void mlp_partial_kernel(const float* __restrict__ pts, int npts,
                        const float* __restrict__ W1, const float* __restrict__ b1,
                        const float* __restrict__ W2, const float* __restrict__ b2,
                        const float* __restrict__ W3, const float* __restrict__ b3,
                        float* __restrict__ partials)
{
    float acc[64];
#pragma unroll
    for (int j = 0; j < 64; ++j) acc[j] = 0.0f;

    const int nth = gridDim.x * blockDim.x;
    for (int i = blockIdx.x * blockDim.x + threadIdx.x; i < npts; i += nth) {
        const float x0 = pts[3 * i + 0];
        const float x1 = pts[3 * i + 1];
        const float x2 = pts[3 * i + 2];

        float h1[16];
#pragma unroll
        for (int j = 0; j < 16; ++j) {
            float s = fmaf(x2, W1[3 * j + 2],
                      fmaf(x1, W1[3 * j + 1],
                      fmaf(x0, W1[3 * j + 0], b1[j])));
            h1[j] = fmaxf(s, 0.0f);
        }

        float h2[32];
#pragma unroll
        for (int j = 0; j < 32; ++j) {
            float s0 = b2[j], s1 = 0.0f;   // 2 chains hide 4-cyc FMA latency
#pragma unroll
            for (int k = 0; k < 16; k += 2) {
                s0 = fmaf(h1[k],     W2[16 * j + k],     s0);
                s1 = fmaf(h1[k + 1], W2[16 * j + k + 1], s1);
            }
            h2[j] = fmaxf(s0 + s1, 0.0f);
        }

#pragma unroll
        for (int j = 0; j < 64; ++j) {
            float s0 = b3[j], s1 = 0.0f;
#pragma unroll
            for (int k = 0; k < 32; k += 2) {
                s0 = fmaf(h2[k],     W3[32 * j + k],     s0);
                s1 = fmaf(h2[k + 1], W3[32 * j + k + 1], s1);
            }
            acc[j] += fmaxf(s0 + s1, 0.0f);
        }
    }

    // 64-lane butterfly reduce of each acc[j] (once per thread lifetime)
#pragma unroll
    for (int j = 0; j < 64; ++j) {
        float v = acc[j];
        v += __shfl_xor(v, 1);
        v += __shfl_xor(v, 2);
        v += __shfl_xor(v, 4);
        v += __shfl_xor(v, 8);
        v += __shfl_xor(v, 16);
        v += __shfl_xor(v, 32);
        acc[j] = v;
    }

    __shared__ float red[4][64];
    const int lane = threadIdx.x & 63;
    const int wave = threadIdx.x >> 6;
    if (lane == 0) {
#pragma unroll
        for (int j = 0; j < 64; ++j) red[wave][j] = acc[j];
    }
    __syncthreads();
    if (threadIdx.x < 64) {
        const int j = threadIdx.x;
        partials[(size_t)blockIdx.x * 64 + j] =
            red[0][j] + red[1][j] + red[2][j] + red[3][j];
    }
}

// Sum the per-block partials, divide by N, apply the (linear) layer 4.
__global__ __launch_bounds__(256)
void finalize_kernel(const float* __restrict__ partials, int nblocks, float inv_n,
                     const float* __restrict__ W4, const float* __restrict__ b4,
                     float* __restrict__ out)
{
    __shared__ float colsum[4][64];
    __shared__ float meanv[64];
    const int t = threadIdx.x;          // 256 threads, 1 block
    const int j = t & 63, part = t >> 6;

    float s = 0.0f;
    for (int b = part; b < nblocks; b += 4) s += partials[(size_t)b * 64 + j];
    colsum[part][j] = s;
    __syncthreads();

    if (t < 64)
        meanv[t] = (colsum[0][t] + colsum[1][t] + colsum[2][t] + colsum[3][t]) * inv_n;
    __syncthreads();

    if (t < 128) {
        float s0 = b4[t], s1 = 0.0f;
#pragma unroll
        for (int k = 0; k < 64; k += 2) {
            s0 = fmaf(W4[64 * t + k],     meanv[k],     s0);
            s1 = fmaf(W4[64 * t + k + 1], meanv[k + 1], s1);
        }
        out[t] = s0 + s1;
    }
}

extern "C" void kernel_launch(void* const* d_in, const int* in_sizes, int n_in,
                              void* d_out, int out_size, void* d_ws, size_t ws_size,
                              hipStream_t stream)
{
    const float* pts = (const float*)d_in[0];
    const float* W1  = (const float*)d_in[1];
    const float* b1  = (const float*)d_in[2];
    const float* W2  = (const float*)d_in[3];
    const float* b2  = (const float*)d_in[4];
    const float* W3  = (const float*)d_in[5];
    const float* b3  = (const float*)d_in[6];
    const float* W4  = (const float*)d_in[7];
    const float* b4  = (const float*)d_in[8];

    const int npts = in_sizes[0] / 3;     // 2,000,000
    float* partials = (float*)d_ws;       // GRID1 x 64 floats (fully overwritten)

    mlp_partial_kernel<<<GRID1, 256, 0, stream>>>(pts, npts, W1, b1, W2, b2, W3, b3, partials);
    finalize_kernel<<<1, 256, 0, stream>>>(partials, GRID1, 1.0f / (float)npts,
                                           W4, b4, (float*)d_out);
}

// Round 4
// 326.987 us; speedup vs baseline: 1.3866x; 1.3866x over previous
//
#include <hip/hip_runtime.h>

// Encoder: 4-layer MLP (3->16->32->64->128) + mean-pool over 2M points.
// Layer 4 is linear and mean is linear => apply W4/b4 AFTER pooling.
// Per-point work: L1+L2+L3 ~ 2900 VALU inst; f32-VALU roofline ~75 us.
//
// Round-3 lesson (from counters): WRITE_SIZE 20 MB = 160 B/thread written
// ONCE and re-read each iteration => LICM hoisted the ~2700 loop-invariant
// weight loads into registers and spilled ~40/thread to scratch. Neither
// launch_bounds nor waves_per_eu touches that. Fix: asm memory clobber in
// the point loop kills LICM; weights re-load per iteration as wave-uniform
// s_loads from the scalar cache (10.4 KB, hot), overlapped with VALU by
// the scalar pipe. acc/h1/h2 are SROA'd SSA values -> unaffected.

#define GRID1 1024   // 4 blocks/CU

__global__ __launch_bounds__(256)
void mlp_partial_kernel(const float* __restrict__ pts, int npts,
                        const float* __restrict__ W1, const float* __restrict__ b1,
                        const float* __restrict__ W2, const float* __restrict__ b2,
                        const float* __restrict__ W3, const float* __restrict__ b3,
                        float* __restrict__ partials)
{
    float acc[64];
#pragma unroll
    for (int j = 0; j < 64; ++j) acc[j] = 0.0f;

    const int nth = gridDim.x * blockDim.x;
    for (int i = blockIdx.x * blockDim.x + threadIdx.x; i < npts; i += nth) {
        // Defeat LICM: force all weight loads to stay inside the loop
        // (re-issued as scalar-cache s_loads) instead of being hoisted
        // into registers and spilled to scratch.
        asm volatile("" ::: "memory");

        const float x0 = pts[3 * i + 0];
        const float x1 = pts[3 * i + 1];
        const float x2 = pts[3 * i + 2];

        float h1[16];
#pragma unroll
        for (int j = 0; j < 16; ++j) {
            float s = fmaf(x2, W1[3 * j + 2],
                      fmaf(x1, W1[3 * j + 1],
                      fmaf(x0, W1[3 * j + 0], b1[j])));
            h1[j] = fmaxf(s, 0.0f);
        }

        float h2[32];
#pragma unroll
        for (int j = 0; j < 32; ++j) {
            float s0 = b2[j], s1 = 0.0f;   // 2 chains hide 4-cyc FMA latency
#pragma unroll
            for (int k = 0; k < 16; k += 2) {
                s0 = fmaf(h1[k],     W2[16 * j + k],     s0);
                s1 = fmaf(h1[k + 1], W2[16 * j + k + 1], s1);
            }
            h2[j] = fmaxf(s0 + s1, 0.0f);
        }

#pragma unroll
        for (int j = 0; j < 64; ++j) {
            float s0 = b3[j], s1 = 0.0f;
#pragma unroll
            for (int k = 0; k < 32; k += 2) {
                s0 = fmaf(h2[k],     W3[32 * j + k],     s0);
                s1 = fmaf(h2[k + 1], W3[32 * j + k + 1], s1);
            }
            acc[j] += fmaxf(s0 + s1, 0.0f);
        }
    }

    // 64-lane butterfly reduce of each acc[j] (once per thread lifetime)
#pragma unroll
    for (int j = 0; j < 64; ++j) {
        float v = acc[j];
        v += __shfl_xor(v, 1);
        v += __shfl_xor(v, 2);
        v += __shfl_xor(v, 4);
        v += __shfl_xor(v, 8);
        v += __shfl_xor(v, 16);
        v += __shfl_xor(v, 32);
        acc[j] = v;
    }

    __shared__ float red[4][64];
    const int lane = threadIdx.x & 63;
    const int wave = threadIdx.x >> 6;
    if (lane == 0) {
#pragma unroll
        for (int j = 0; j < 64; ++j) red[wave][j] = acc[j];
    }
    __syncthreads();
    if (threadIdx.x < 64) {
        const int j = threadIdx.x;
        partials[(size_t)blockIdx.x * 64 + j] =
            red[0][j] + red[1][j] + red[2][j] + red[3][j];
    }
}

// Sum the per-block partials, divide by N, apply the (linear) layer 4.
__global__ __launch_bounds__(256)
void finalize_kernel(const float* __restrict__ partials, int nblocks, float inv_n,
                     const float* __restrict__ W4, const float* __restrict__ b4,
                     float* __restrict__ out)
{
    __shared__ float colsum[4][64];
    __shared__ float meanv[64];
    const int t = threadIdx.x;          // 256 threads, 1 block
    const int j = t & 63, part = t >> 6;

    float s = 0.0f;
    for (int b = part; b < nblocks; b += 4) s += partials[(size_t)b * 64 + j];
    colsum[part][j] = s;
    __syncthreads();

    if (t < 64)
        meanv[t] = (colsum[0][t] + colsum[1][t] + colsum[2][t] + colsum[3][t]) * inv_n;
    __syncthreads();

    if (t < 128) {
        float s0 = b4[t], s1 = 0.0f;
#pragma unroll
        for (int k = 0; k < 64; k += 2) {
            s0 = fmaf(W4[64 * t + k],     meanv[k],     s0);
            s1 = fmaf(W4[64 * t + k + 1], meanv[k + 1], s1);
        }
        out[t] = s0 + s1;
    }
}

extern "C" void kernel_launch(void* const* d_in, const int* in_sizes, int n_in,
                              void* d_out, int out_size, void* d_ws, size_t ws_size,
                              hipStream_t stream)
{
    const float* pts = (const float*)d_in[0];
    const float* W1  = (const float*)d_in[1];
    const float* b1  = (const float*)d_in[2];
    const float* W2  = (const float*)d_in[3];
    const float* b2  = (const float*)d_in[4];
    const float* W3  = (const float*)d_in[5];
    const float* b3  = (const float*)d_in[6];
    const float* W4  = (const float*)d_in[7];
    const float* b4  = (const float*)d_in[8];

    const int npts = in_sizes[0] / 3;     // 2,000,000
    float* partials = (float*)d_ws;       // GRID1 x 64 floats (fully overwritten)

    mlp_partial_kernel<<<GRID1, 256, 0, stream>>>(pts, npts, W1, b1, W2, b2, W3, b3, partials);
    finalize_kernel<<<1, 256, 0, stream>>>(partials, GRID1, 1.0f / (float)npts,
                                           W4, b4, (float*)d_out);
}

// Round 6
// 260.366 us; speedup vs baseline: 1.7413x; 1.2559x over previous
//
#include <hip/hip_runtime.h>

// Encoder: 4-layer MLP (3->16->32->64->128) + mean-pool over 2M points.
// Layer 4 is linear and mean is linear => apply W4/b4 AFTER pooling.
// Per-point work: L1+L2+L3 ~ 2900 VALU inst; f32-VALU roofline ~75 us.
//
// Round-4 state: asm-clobber kills LICM weight-spill (WRITE 20MB->0.25MB,
// confirmed). Remaining stall: s_load (scalar-cache) latency with only
// ~2 waves/SIMD resident (VALUBusy 47%, Occupancy 26%). VGPR=68 allows
// 7 waves/SIMD -> raise grid to 7 blocks/CU and let TLP hide lgkmcnt.
// Also: single-block finalize was ~50-100us (scaled with nblocks) ->
// replaced by transposed partials + 64-block column reduce + tiny W4.
// (Round 5 was an infra failure — this source is the unchanged resubmit.)

#define GRID1 1792   // 7 blocks/CU x 256 CUs = 7 waves/SIMD (VGPR 68 -> fits)

__global__ __launch_bounds__(256)
void mlp_partial_kernel(const float* __restrict__ pts, int npts,
                        const float* __restrict__ W1, const float* __restrict__ b1,
                        const float* __restrict__ W2, const float* __restrict__ b2,
                        const float* __restrict__ W3, const float* __restrict__ b3,
                        float* __restrict__ partialsT)   // [64][GRID1]
{
    float acc[64];
#pragma unroll
    for (int j = 0; j < 64; ++j) acc[j] = 0.0f;

    const int nth = gridDim.x * blockDim.x;
    for (int i = blockIdx.x * blockDim.x + threadIdx.x; i < npts; i += nth) {
        // Defeat LICM: keep weight loads inside the loop as wave-uniform
        // s_loads (scalar cache, hot) instead of hoisted+spilled VGPRs.
        asm volatile("" ::: "memory");

        const float x0 = pts[3 * i + 0];
        const float x1 = pts[3 * i + 1];
        const float x2 = pts[3 * i + 2];

        float h1[16];
#pragma unroll
        for (int j = 0; j < 16; ++j) {
            float s = fmaf(x2, W1[3 * j + 2],
                      fmaf(x1, W1[3 * j + 1],
                      fmaf(x0, W1[3 * j + 0], b1[j])));
            h1[j] = fmaxf(s, 0.0f);
        }

        float h2[32];
#pragma unroll
        for (int j = 0; j < 32; ++j) {
            float s0 = b2[j], s1 = 0.0f;   // 2 chains hide 4-cyc FMA latency
#pragma unroll
            for (int k = 0; k < 16; k += 2) {
                s0 = fmaf(h1[k],     W2[16 * j + k],     s0);
                s1 = fmaf(h1[k + 1], W2[16 * j + k + 1], s1);
            }
            h2[j] = fmaxf(s0 + s1, 0.0f);
        }

#pragma unroll
        for (int j = 0; j < 64; ++j) {
            float s0 = b3[j], s1 = 0.0f;
#pragma unroll
            for (int k = 0; k < 32; k += 2) {
                s0 = fmaf(h2[k],     W3[32 * j + k],     s0);
                s1 = fmaf(h2[k + 1], W3[32 * j + k + 1], s1);
            }
            acc[j] += fmaxf(s0 + s1, 0.0f);
        }
    }

    // 64-lane butterfly reduce of each acc[j] (once per thread lifetime)
#pragma unroll
    for (int j = 0; j < 64; ++j) {
        float v = acc[j];
        v += __shfl_xor(v, 1);
        v += __shfl_xor(v, 2);
        v += __shfl_xor(v, 4);
        v += __shfl_xor(v, 8);
        v += __shfl_xor(v, 16);
        v += __shfl_xor(v, 32);
        acc[j] = v;
    }

    __shared__ float red[4][64];
    const int lane = threadIdx.x & 63;
    const int wave = threadIdx.x >> 6;
    if (lane == 0) {
#pragma unroll
        for (int j = 0; j < 64; ++j) red[wave][j] = acc[j];
    }
    __syncthreads();
    if (threadIdx.x < 64) {
        const int j = threadIdx.x;
        // transposed: column j contiguous over blocks -> stage2 reads coalesce
        partialsT[(size_t)j * GRID1 + blockIdx.x] =
            red[0][j] + red[1][j] + red[2][j] + red[3][j];
    }
}

// Stage 2: 64 blocks; block j sums partialsT[j][0..nblocks) -> mean[j]
__global__ __launch_bounds__(256)
void colsum_kernel(const float* __restrict__ partialsT, int nblocks, float inv_n,
                   float* __restrict__ meanv)
{
    const int j = blockIdx.x;           // 0..63
    const int t = threadIdx.x;          // 256 threads
    float s = 0.0f;
    for (int b = t; b < nblocks; b += 256)
        s += partialsT[(size_t)j * nblocks + b];

    s += __shfl_xor(s, 1);
    s += __shfl_xor(s, 2);
    s += __shfl_xor(s, 4);
    s += __shfl_xor(s, 8);
    s += __shfl_xor(s, 16);
    s += __shfl_xor(s, 32);

    __shared__ float red[4];
    if ((t & 63) == 0) red[t >> 6] = s;
    __syncthreads();
    if (t == 0)
        meanv[j] = (red[0] + red[1] + red[2] + red[3]) * inv_n;
}

// Stage 3: apply the (linear) layer 4 on the pooled 64-vector.
__global__ __launch_bounds__(128)
void layer4_kernel(const float* __restrict__ meanv,
                   const float* __restrict__ W4, const float* __restrict__ b4,
                   float* __restrict__ out)
{
    const int t = threadIdx.x;          // 128 threads, 1 block
    float s0 = b4[t], s1 = 0.0f;
#pragma unroll
    for (int k = 0; k < 64; k += 2) {
        s0 = fmaf(W4[64 * t + k],     meanv[k],     s0);
        s1 = fmaf(W4[64 * t + k + 1], meanv[k + 1], s1);
    }
    out[t] = s0 + s1;
}

extern "C" void kernel_launch(void* const* d_in, const int* in_sizes, int n_in,
                              void* d_out, int out_size, void* d_ws, size_t ws_size,
                              hipStream_t stream)
{
    const float* pts = (const float*)d_in[0];
    const float* W1  = (const float*)d_in[1];
    const float* b1  = (const float*)d_in[2];
    const float* W2  = (const float*)d_in[3];
    const float* b2  = (const float*)d_in[4];
    const float* W3  = (const float*)d_in[5];
    const float* b3  = (const float*)d_in[6];
    const float* W4  = (const float*)d_in[7];
    const float* b4  = (const float*)d_in[8];

    const int npts = in_sizes[0] / 3;         // 2,000,000
    float* partialsT = (float*)d_ws;          // 64 x GRID1 floats
    float* meanv     = partialsT + (size_t)64 * GRID1;

    mlp_partial_kernel<<<GRID1, 256, 0, stream>>>(pts, npts, W1, b1, W2, b2, W3, b3, partialsT);
    colsum_kernel<<<64, 256, 0, stream>>>(partialsT, GRID1, 1.0f / (float)npts, meanv);
    layer4_kernel<<<1, 128, 0, stream>>>(meanv, W4, b4, (float*)d_out);
}

// Round 9
// 153.230 us; speedup vs baseline: 2.9588x; 1.6992x over previous
//
#include <hip/hip_runtime.h>

// Encoder: 4-layer MLP (3->16->32->64->128) + mean-pool over 2M points.
// L4 linear + mean linear => W4/b4 applied after pooling.
//
// Round-7 lesson: absmax=NaN with math that cannot generate NaN => the
// L3 LDS fragment reads (u32 loads from an unsigned-short array) were a
// strict-aliasing violation; TBAA let the scheduler hoist ds_read_b32
// above the ds_write_b16s -> reads of uninitialized LDS (arbitrary bits,
// incl. bf16-NaN patterns). Fix: may_alias on the u32 LDS reads restores
// the write->read dependence. (Round 8 was an infra timeout — this is
// the unchanged resubmit of that fix.)
//
// Design: 32-pt M-tiles, mfma_f32_32x32x16_bf16.
//  - L1 (K=3) on VALU in f32; shfl_xor(32) repack -> A2 frags.
//  - Weights hi/lo bf16 split (2x MFMA) => ~f32 weight precision;
//    activation bf16 rounding is symmetric -> killed by mean-pool.
//  - L2->L3 transpose via per-wave LDS (XOR-swizzled 4-short groups).
//  - Pool in C-layout (elementwise acc[16]) -> no output transpose.
// A/B frag mapping (derived m162-scaling, 2 independent derivations):
//   lane l, elem e: row/col = l&31, k = 4*(l>>5) + (e&3) + 8*(e>>2).
// C/D (m74/m101 verified): col = l&31, row = (r&3) + 8*(r>>2) + 4*(l>>5).

typedef __attribute__((ext_vector_type(8)))  short short8;
typedef __attribute__((ext_vector_type(16))) float f32x16;
typedef unsigned int __attribute__((may_alias)) u32a;   // legal LDS type-punning

#define GRID1 1024
#define WAVES_TOT (GRID1 * 4)

union frag_u { short8 s8; unsigned int u[4]; };

__device__ __forceinline__ unsigned int bf16rne(float f) {
    unsigned int u = __builtin_bit_cast(unsigned int, f);
    return (u + 0x7FFFu + ((u >> 16) & 1u)) >> 16;   // round-to-nearest-even
}
__device__ __forceinline__ unsigned int packbf(float a, float b) {
    return bf16rne(a) | (bf16rne(b) << 16);
}
// hi/lo split: hi = bf16(w); lo = bf16(w - f32(hi))  (~17 mantissa bits total)
__device__ __forceinline__ void split_pair(float a, float b, unsigned &hi, unsigned &lo) {
    unsigned ha = bf16rne(a), hb = bf16rne(b);
    float fa = __builtin_bit_cast(float, ha << 16);
    float fb = __builtin_bit_cast(float, hb << 16);
    hi = ha | (hb << 16);
    lo = packbf(a - fa, b - fb);
}
// XOR-swizzle of 4-short groups within a 32-short row (breaks 64B-stride conflicts)
__device__ __forceinline__ int swz(int row, int grp) { return ((grp ^ (row & 7)) << 2); }

__global__ __launch_bounds__(256)
void mlp_mfma_kernel(const float* __restrict__ pts, int npass,
                     const float* __restrict__ W1, const float* __restrict__ b1,
                     const float* __restrict__ W2, const float* __restrict__ b2,
                     const float* __restrict__ W3, const float* __restrict__ b3,
                     float* __restrict__ partialsT)   // [64][GRID1]
{
    const int tid  = threadIdx.x;
    const int wv   = tid >> 6;
    const int lane = tid & 63;
    const int kh   = lane >> 5;      // K-half selector
    const int c    = lane & 31;      // row (A) / col (B,D) within tile

    __shared__ unsigned short h2buf[4][64 * 32];   // per-wave [64 pts][32 neurons] bf16
    __shared__ float bred[4][64];

    // ---- weight fragments (built once; no per-point reload) ----
    frag_u w2hi, w2lo;
    {
        const float* r = W2 + c * 16 + 4 * kh;     // W2[c][k-chunks {4kh..},{8+4kh..}]
        split_pair(r[0],  r[1],  w2hi.u[0], w2lo.u[0]);
        split_pair(r[2],  r[3],  w2hi.u[1], w2lo.u[1]);
        split_pair(r[8],  r[9],  w2hi.u[2], w2lo.u[2]);
        split_pair(r[10], r[11], w2hi.u[3], w2lo.u[3]);
    }
    frag_u w3hi[2][2], w3lo[2][2];
#pragma unroll
    for (int n = 0; n < 2; ++n)
#pragma unroll
        for (int s = 0; s < 2; ++s) {
            const float* r = W3 + (32 * n + c) * 32 + 16 * s + 4 * kh;
            split_pair(r[0],  r[1],  w3hi[n][s].u[0], w3lo[n][s].u[0]);
            split_pair(r[2],  r[3],  w3hi[n][s].u[1], w3lo[n][s].u[1]);
            split_pair(r[8],  r[9],  w3hi[n][s].u[2], w3lo[n][s].u[2]);
            split_pair(r[10], r[11], w3hi[n][s].u[3], w3lo[n][s].u[3]);
        }
    const float b2s  = b2[c];
    const float b3s0 = b3[c], b3s1 = b3[32 + c];

    f32x16 accA, accB;                 // pooled relu(h3), C-layout, cols 0-31 / 32-63
#pragma unroll
    for (int r = 0; r < 16; ++r) { accA[r] = 0.f; accB[r] = 0.f; }

    const int wg = blockIdx.x * 4 + wv;
    for (int p = wg; p < npass; p += WAVES_TOT) {   // 64 points per pass per wave
        const float* pp = pts + (size_t)(p * 64 + lane) * 3;
        const float x0 = pp[0], x1 = pp[1], x2 = pp[2];

        // ---- L1 on VALU (f32 exact), pack h1 -> bf16 dwords ----
        unsigned d[8];
#pragma unroll
        for (int v = 0; v < 8; ++v) {
            const int ja = 2 * v, jb = 2 * v + 1;
            float ha = fmaxf(fmaf(x2, W1[ja*3+2], fmaf(x1, W1[ja*3+1], fmaf(x0, W1[ja*3+0], b1[ja]))), 0.f);
            float hb = fmaxf(fmaf(x2, W1[jb*3+2], fmaf(x1, W1[jb*3+1], fmaf(x0, W1[jb*3+0], b1[jb]))), 0.f);
            d[v] = packbf(ha, hb);
        }
        unsigned sx[8];
#pragma unroll
        for (int v = 0; v < 8; ++v) sx[v] = (unsigned)__shfl_xor((int)d[v], 32);

        // A2 frags (M-tile 0: points 0-31, tile 1: points 32-63)
        frag_u a2[2];
        a2[0].u[0] = kh ? sx[2] : d[0];
        a2[0].u[1] = kh ? sx[3] : d[1];
        a2[0].u[2] = kh ? sx[6] : d[4];
        a2[0].u[3] = kh ? sx[7] : d[5];
        a2[1].u[0] = kh ? d[2] : sx[0];
        a2[1].u[1] = kh ? d[3] : sx[1];
        a2[1].u[2] = kh ? d[6] : sx[4];
        a2[1].u[3] = kh ? d[7] : sx[5];

        // ---- L2: 2 MFMA per tile (hi/lo); bias preloaded into C ----
#pragma unroll
        for (int t = 0; t < 2; ++t) {
            f32x16 d2;
#pragma unroll
            for (int r = 0; r < 16; ++r) d2[r] = b2s;
            d2 = __builtin_amdgcn_mfma_f32_32x32x16_bf16(a2[t].s8, w2hi.s8, d2, 0, 0, 0);
            d2 = __builtin_amdgcn_mfma_f32_32x32x16_bf16(a2[t].s8, w2lo.s8, d2, 0, 0, 0);
#pragma unroll
            for (int r = 0; r < 16; ++r) {
                const int row = (r & 3) + 8 * (r >> 2) + 4 * kh + 32 * t;
                const float v = fmaxf(d2[r], 0.f);
                h2buf[wv][row * 32 + swz(row, c >> 2) + (c & 3)] = (unsigned short)bf16rne(v);
            }
        }

        // ---- L3: LDS transpose read -> 8 MFMA per tile; pool in C-layout ----
#pragma unroll
        for (int t = 0; t < 2; ++t) {
            frag_u a3[2];
#pragma unroll
            for (int s = 0; s < 2; ++s) {
                const int row = 32 * t + c;
                const unsigned short* r1 = &h2buf[wv][row * 32 + swz(row, 4 * s + kh)];
                const unsigned short* r2 = &h2buf[wv][row * 32 + swz(row, 4 * s + 2 + kh)];
                a3[s].u[0] = *(const u32a*)(r1 + 0);
                a3[s].u[1] = *(const u32a*)(r1 + 2);
                a3[s].u[2] = *(const u32a*)(r2 + 0);
                a3[s].u[3] = *(const u32a*)(r2 + 2);
            }
            f32x16 d3a, d3b;
#pragma unroll
            for (int r = 0; r < 16; ++r) { d3a[r] = b3s0; d3b[r] = b3s1; }
#pragma unroll
            for (int s = 0; s < 2; ++s) {
                d3a = __builtin_amdgcn_mfma_f32_32x32x16_bf16(a3[s].s8, w3hi[0][s].s8, d3a, 0, 0, 0);
                d3a = __builtin_amdgcn_mfma_f32_32x32x16_bf16(a3[s].s8, w3lo[0][s].s8, d3a, 0, 0, 0);
                d3b = __builtin_amdgcn_mfma_f32_32x32x16_bf16(a3[s].s8, w3hi[1][s].s8, d3b, 0, 0, 0);
                d3b = __builtin_amdgcn_mfma_f32_32x32x16_bf16(a3[s].s8, w3lo[1][s].s8, d3b, 0, 0, 0);
            }
#pragma unroll
            for (int r = 0; r < 16; ++r) {
                accA[r] += fmaxf(d3a[r], 0.f);
                accB[r] += fmaxf(d3b[r], 0.f);
            }
        }
    }

    // ---- per-wave column sums (rows already summed elementwise in acc) ----
    float sa = 0.f, sb = 0.f;
#pragma unroll
    for (int r = 0; r < 16; ++r) { sa += accA[r]; sb += accB[r]; }
    sa += __shfl_xor(sa, 32);          // fold the two row-halves
    sb += __shfl_xor(sb, 32);
    if (lane < 32) { bred[wv][c] = sa; bred[wv][32 + c] = sb; }
    __syncthreads();
    if (tid < 64) {
        partialsT[(size_t)tid * GRID1 + blockIdx.x] =
            bred[0][tid] + bred[1][tid] + bred[2][tid] + bred[3][tid];
    }
}

// Fused tail: column-sum partialsT [64][GRID1], mean, apply linear L4.
__global__ __launch_bounds__(256)
void finalize_kernel(const float* __restrict__ partialsT, float inv_n,
                     const float* __restrict__ W4, const float* __restrict__ b4,
                     float* __restrict__ out)
{
    __shared__ float ps[64][4];
    __shared__ float meanv[64];
    const int t = threadIdx.x;          // 256 threads, 1 block
    const int j = t >> 2, q = t & 3;

    float s = 0.f;
    const float* row = partialsT + (size_t)j * GRID1 + q * (GRID1 / 4);
    for (int i = 0; i < GRID1 / 4; ++i) s += row[i];
    ps[j][q] = s;
    __syncthreads();
    if (t < 64) meanv[t] = (ps[t][0] + ps[t][1] + ps[t][2] + ps[t][3]) * inv_n;
    __syncthreads();
    if (t < 128) {
        float s0 = b4[t], s1 = 0.f;
#pragma unroll
        for (int k = 0; k < 64; k += 2) {
            s0 = fmaf(W4[64 * t + k],     meanv[k],     s0);
            s1 = fmaf(W4[64 * t + k + 1], meanv[k + 1], s1);
        }
        out[t] = s0 + s1;
    }
}

extern "C" void kernel_launch(void* const* d_in, const int* in_sizes, int n_in,
                              void* d_out, int out_size, void* d_ws, size_t ws_size,
                              hipStream_t stream)
{
    const float* pts = (const float*)d_in[0];
    const float* W1  = (const float*)d_in[1];
    const float* b1  = (const float*)d_in[2];
    const float* W2  = (const float*)d_in[3];
    const float* b2  = (const float*)d_in[4];
    const float* W3  = (const float*)d_in[5];
    const float* b3  = (const float*)d_in[6];
    const float* W4  = (const float*)d_in[7];
    const float* b4  = (const float*)d_in[8];

    const int npts  = in_sizes[0] / 3;     // 2,000,000
    const int npass = npts / 64;           // 31,250 (exact)
    float* partialsT = (float*)d_ws;       // 64 x GRID1 floats (fully overwritten)

    mlp_mfma_kernel<<<GRID1, 256, 0, stream>>>(pts, npass, W1, b1, W2, b2, W3, b3, partialsT);
    finalize_kernel<<<1, 256, 0, stream>>>(partialsT, 1.0f / (float)npts, W4, b4, (float*)d_out);
}

// Round 13
// 144.061 us; speedup vs baseline: 3.1472x; 1.0636x over previous
//
#include <hip/hip_runtime.h>

// Encoder: 4-layer MLP (3->16->32->64->128) + mean-pool over 2M points.
// L4 linear + mean linear => W4/b4 applied after pooling.
//
// SWAPPED-OPERAND MFMA CHAINING (structure unchanged from round 12):
// L2 computed as D2^T = W2(A) x h1^T(B). The C/D row map
// (r&3)+8*(r>>2)+4*kh is element-identical to the B-frag k map
// 4*kh+(e&3)+8*(e>>2), so relu(D2^T), packed to bf16, IS the L3
// B-operand in-register: no LDS transpose, no bank conflicts.
//
// Round-12 lesson (isolation in progress): round 12 produced absmax=NaN.
// All index/bounds paths re-derived clean; finite relu'd bf16 math cannot
// make NaN. The only mechanical delta vs the passing round-9 kernel was
// the inline-asm v_cvt_pk_bf16_f32 packing. THIS round replaces all asm
// cvtpk with round-9's HW-verified manual packbf (pure integer ops) --
// one variable. If it passes, the asm was the culprit (cf. learn_hip
// m240: don't hand-write cvt_pk).

typedef __attribute__((ext_vector_type(8)))  short short8;
typedef __attribute__((ext_vector_type(16))) float f32x16;

#define GRID1 768                 // 3 blocks/CU
#define NWAVES (GRID1 * 4)

union frag_u { short8 s8; unsigned int u[4]; };

__device__ __forceinline__ unsigned int bf16rne(float f) {
    unsigned int u = __builtin_bit_cast(unsigned int, f);
    return (u + 0x7FFFu + ((u >> 16) & 1u)) >> 16;   // round-to-nearest-even
}
__device__ __forceinline__ unsigned int packbf(float a, float b) {
    return bf16rne(a) | (bf16rne(b) << 16);          // a -> lo16, b -> hi16
}

__global__ __launch_bounds__(256)
void mlp_mfma2_kernel(const float* __restrict__ pts, int npass,
                      const float* __restrict__ W1, const float* __restrict__ b1,
                      const float* __restrict__ W2, const float* __restrict__ b2,
                      const float* __restrict__ W3, const float* __restrict__ b3,
                      float* __restrict__ partialsT)   // [64][GRID1]
{
    const int tid  = threadIdx.x;
    const int wv   = tid >> 6;
    const int lane = tid & 63;
    const int kh   = lane >> 5;     // K-half selector
    const int c    = lane & 31;     // A-row / B-col / D-col within tile

    __shared__ float bred[4][64];

    // ---- weight A-fragments (built once, register-resident) ----
    // A[row=c][k], k = 4*kh + (e&3) + 8*(e>>2); pairs packed lo-first.
    frag_u w2f;
    {
        const float* r = W2 + c * 16 + 4 * kh;
        w2f.u[0] = packbf(r[0],  r[1]);
        w2f.u[1] = packbf(r[2],  r[3]);
        w2f.u[2] = packbf(r[8],  r[9]);
        w2f.u[3] = packbf(r[10], r[11]);
    }
    frag_u w3f[2][2];               // [n-tile][k-step]
#pragma unroll
    for (int nt = 0; nt < 2; ++nt)
#pragma unroll
        for (int s = 0; s < 2; ++s) {
            const float* r = W3 + (32 * nt + c) * 32 + 16 * s + 4 * kh;
            w3f[nt][s].u[0] = packbf(r[0],  r[1]);
            w3f[nt][s].u[1] = packbf(r[2],  r[3]);
            w3f[nt][s].u[2] = packbf(r[8],  r[9]);
            w3f[nt][s].u[3] = packbf(r[10], r[11]);
        }

    // ---- bias vectors in C/D row layout (row = (r&3)+8*(r>>2)+4*kh) ----
    f32x16 b2v, b3v0, b3v1;
#pragma unroll
    for (int r = 0; r < 16; ++r) {
        const int n = (r & 3) + 8 * (r >> 2) + 4 * kh;
        b2v[r]  = b2[n];
        b3v0[r] = b3[n];
        b3v1[r] = b3[32 + n];
    }

    f32x16 acc0, acc1;              // pooled relu(h3), rows = neurons, col = c
#pragma unroll
    for (int r = 0; r < 16; ++r) { acc0[r] = 0.f; acc1[r] = 0.f; }

    const int wg = blockIdx.x * 4 + wv;
    for (int p = wg; p < npass; p += NWAVES) {      // 64 points per pass
        const float* pp = pts + (size_t)(p * 64 + lane) * 3;
        const float x0 = pp[0], x1 = pp[1], x2 = pp[2];

        // ---- L1 on VALU (f32 exact) ----
        float h1[16];
#pragma unroll
        for (int j = 0; j < 16; ++j)
            h1[j] = fmaxf(fmaf(x2, W1[3*j+2],
                          fmaf(x1, W1[3*j+1],
                          fmaf(x0, W1[3*j+0], b1[j]))), 0.f);

        const unsigned q0 = packbf(h1[0],  h1[1]),  q1 = packbf(h1[2],  h1[3]);
        const unsigned q2 = packbf(h1[4],  h1[5]),  q3 = packbf(h1[6],  h1[7]);
        const unsigned q4 = packbf(h1[8],  h1[9]),  q5 = packbf(h1[10], h1[11]);
        const unsigned q6 = packbf(h1[12], h1[13]), q7 = packbf(h1[14], h1[15]);

        const unsigned s0 = (unsigned)__shfl_xor((int)q0, 32);
        const unsigned s1 = (unsigned)__shfl_xor((int)q1, 32);
        const unsigned s2 = (unsigned)__shfl_xor((int)q2, 32);
        const unsigned s3 = (unsigned)__shfl_xor((int)q3, 32);
        const unsigned s4 = (unsigned)__shfl_xor((int)q4, 32);
        const unsigned s5 = (unsigned)__shfl_xor((int)q5, 32);
        const unsigned s6 = (unsigned)__shfl_xor((int)q6, 32);
        const unsigned s7 = (unsigned)__shfl_xor((int)q7, 32);

        // ---- two point-tiles (cols 0-31 = points p*64+0..31, then +32) ----
#pragma unroll
        for (int ct = 0; ct < 2; ++ct) {
            frag_u bf;                              // B[k][col=point c]
            if (ct == 0) {
                bf.u[0] = kh ? s2 : q0;  bf.u[1] = kh ? s3 : q1;
                bf.u[2] = kh ? s6 : q4;  bf.u[3] = kh ? s7 : q5;
            } else {
                bf.u[0] = kh ? q2 : s0;  bf.u[1] = kh ? q3 : s1;
                bf.u[2] = kh ? q6 : s4;  bf.u[3] = kh ? q7 : s5;
            }

            // L2: D2^T[neuron][point] = W2 x h1^T  (bias in C)
            f32x16 t2 = b2v;
            t2 = __builtin_amdgcn_mfma_f32_32x32x16_bf16(w2f.s8, bf.s8, t2, 0, 0, 0);

            // relu + pack: D-rows ARE the L3 B-frag k-positions
            frag_u pa, pb;                          // k-steps s=0 (n 0-15), s=1 (n 16-31)
#pragma unroll
            for (int e = 0; e < 4; ++e) {
                pa.u[e] = packbf(fmaxf(t2[2*e],     0.f), fmaxf(t2[2*e + 1],     0.f));
                pb.u[e] = packbf(fmaxf(t2[8 + 2*e], 0.f), fmaxf(t2[8 + 2*e + 1], 0.f));
            }

            // L3: D3^T[neuron][point] = W3 x relu(h2)^T, 2 n-tiles x 2 k-steps
            f32x16 t3 = b3v0;
            t3 = __builtin_amdgcn_mfma_f32_32x32x16_bf16(w3f[0][0].s8, pa.s8, t3, 0, 0, 0);
            t3 = __builtin_amdgcn_mfma_f32_32x32x16_bf16(w3f[0][1].s8, pb.s8, t3, 0, 0, 0);
#pragma unroll
            for (int r = 0; r < 16; ++r) acc0[r] += fmaxf(t3[r], 0.f);

            f32x16 t4 = b3v1;
            t4 = __builtin_amdgcn_mfma_f32_32x32x16_bf16(w3f[1][0].s8, pa.s8, t4, 0, 0, 0);
            t4 = __builtin_amdgcn_mfma_f32_32x32x16_bf16(w3f[1][1].s8, pb.s8, t4, 0, 0, 0);
#pragma unroll
            for (int r = 0; r < 16; ++r) acc1[r] += fmaxf(t4[r], 0.f);
        }
    }

    // ---- reduce cols (points) across the 32 lanes of each kh-group ----
#pragma unroll
    for (int r = 0; r < 16; ++r) {
        float a0 = acc0[r], a1 = acc1[r];
        a0 += __shfl_xor(a0, 1);  a1 += __shfl_xor(a1, 1);
        a0 += __shfl_xor(a0, 2);  a1 += __shfl_xor(a1, 2);
        a0 += __shfl_xor(a0, 4);  a1 += __shfl_xor(a1, 4);
        a0 += __shfl_xor(a0, 8);  a1 += __shfl_xor(a1, 8);
        a0 += __shfl_xor(a0, 16); a1 += __shfl_xor(a1, 16);
        if (c == 0) {                       // lanes 0 and 32 (one per kh)
            const int n = (r & 3) + 8 * (r >> 2) + 4 * kh;
            bred[wv][n]      = a0;
            bred[wv][32 + n] = a1;
        }
    }
    __syncthreads();
    if (tid < 64) {
        partialsT[(size_t)tid * GRID1 + blockIdx.x] =
            bred[0][tid] + bred[1][tid] + bred[2][tid] + bred[3][tid];
    }
}

// Fused tail: column-sum partialsT [64][GRID1], mean, apply linear L4.
__global__ __launch_bounds__(256)
void finalize_kernel(const float* __restrict__ partialsT, float inv_n,
                     const float* __restrict__ W4, const float* __restrict__ b4,
                     float* __restrict__ out)
{
    __shared__ float ps[64][4];
    __shared__ float meanv[64];
    const int t = threadIdx.x;          // 256 threads, 1 block
    const int j = t >> 2, q = t & 3;

    float s = 0.f;
    const float* row = partialsT + (size_t)j * GRID1 + q * (GRID1 / 4);
    for (int i = 0; i < GRID1 / 4; ++i) s += row[i];
    ps[j][q] = s;
    __syncthreads();
    if (t < 64) meanv[t] = (ps[t][0] + ps[t][1] + ps[t][2] + ps[t][3]) * inv_n;
    __syncthreads();
    if (t < 128) {
        float s0 = b4[t], s1 = 0.f;
#pragma unroll
        for (int k = 0; k < 64; k += 2) {
            s0 = fmaf(W4[64 * t + k],     meanv[k],     s0);
            s1 = fmaf(W4[64 * t + k + 1], meanv[k + 1], s1);
        }
        out[t] = s0 + s1;
    }
}

extern "C" void kernel_launch(void* const* d_in, const int* in_sizes, int n_in,
                              void* d_out, int out_size, void* d_ws, size_t ws_size,
                              hipStream_t stream)
{
    const float* pts = (const float*)d_in[0];
    const float* W1  = (const float*)d_in[1];
    const float* b1  = (const float*)d_in[2];
    const float* W2  = (const float*)d_in[3];
    const float* b2  = (const float*)d_in[4];
    const float* W3  = (const float*)d_in[5];
    const float* b3  = (const float*)d_in[6];
    const float* W4  = (const float*)d_in[7];
    const float* b4  = (const float*)d_in[8];

    const int npts  = in_sizes[0] / 3;     // 2,000,000
    const int npass = npts / 64;           // 31,250 (exact)
    float* partialsT = (float*)d_ws;       // 64 x GRID1 floats (fully overwritten)

    mlp_mfma2_kernel<<<GRID1, 256, 0, stream>>>(pts, npass, W1, b1, W2, b2, W3, b3, partialsT);
    finalize_kernel<<<1, 256, 0, stream>>>(partialsT, 1.0f / (float)npts, W4, b4, (float*)d_out);
}

// Round 15
// 138.536 us; speedup vs baseline: 3.2727x; 1.0399x over previous
//
#include <hip/hip_runtime.h>
#include <hip/hip_bf16.h>

// Encoder: 4-layer MLP (3->16->32->64->128) + mean-pool over 2M points.
// L4 linear + mean linear => W4/b4 applied after pooling.
//
// SWAPPED-OPERAND MFMA CHAINING (validated round 13, absmax 9.8e-4):
// L2 computed as D2^T = W2(A) x h1^T(B); C/D row map == B-frag k map,
// so relu(D2^T) packed to bf16 IS the L3 B-operand in-register.
//
// Round-14: compile fix only — __builtin_bit_cast rejects __hip_bfloat162
// (not trivially copyable in this ROCm); type-pun via union instead.
// The two round-13 changes are otherwise unchanged and still under test:
// (1) prefetch next pass's 3 point-floats at loop top (VMEM latency hides
// under the pass body); (2) pack via __float22bfloat162_rn -> compiler
// emits v_cvt_pk_bf16_f32 (1 inst/pair vs ~6 manual; m240-safe form).

typedef __attribute__((ext_vector_type(8)))  short short8;
typedef __attribute__((ext_vector_type(16))) float f32x16;

#define GRID1 768                 // 3 blocks/CU; 3 waves/SIMD at VGPR~152
#define NWAVES (GRID1 * 4)

union frag_u { short8 s8; unsigned int u[4]; };

__device__ __forceinline__ unsigned int cvt2(float a, float b) {
    float2 f; f.x = a; f.y = b;                      // a -> lo16, b -> hi16
    union { __hip_bfloat162 h; unsigned int u; } cv;
    cv.h = __float22bfloat162_rn(f);
    return cv.u;
}

__global__ __launch_bounds__(256)
void mlp_mfma2_kernel(const float* __restrict__ pts, int npass,
                      const float* __restrict__ W1, const float* __restrict__ b1,
                      const float* __restrict__ W2, const float* __restrict__ b2,
                      const float* __restrict__ W3, const float* __restrict__ b3,
                      float* __restrict__ partialsT)   // [64][GRID1]
{
    const int tid  = threadIdx.x;
    const int wv   = tid >> 6;
    const int lane = tid & 63;
    const int kh   = lane >> 5;     // K-half selector
    const int c    = lane & 31;     // A-row / B-col / D-col within tile

    __shared__ float bred[4][64];

    // ---- weight A-fragments (built once, register-resident) ----
    // A[row=c][k], k = 4*kh + (e&3) + 8*(e>>2); pairs packed lo-first.
    frag_u w2f;
    {
        const float* r = W2 + c * 16 + 4 * kh;
        w2f.u[0] = cvt2(r[0],  r[1]);
        w2f.u[1] = cvt2(r[2],  r[3]);
        w2f.u[2] = cvt2(r[8],  r[9]);
        w2f.u[3] = cvt2(r[10], r[11]);
    }
    frag_u w3f[2][2];               // [n-tile][k-step]
#pragma unroll
    for (int nt = 0; nt < 2; ++nt)
#pragma unroll
        for (int s = 0; s < 2; ++s) {
            const float* r = W3 + (32 * nt + c) * 32 + 16 * s + 4 * kh;
            w3f[nt][s].u[0] = cvt2(r[0],  r[1]);
            w3f[nt][s].u[1] = cvt2(r[2],  r[3]);
            w3f[nt][s].u[2] = cvt2(r[8],  r[9]);
            w3f[nt][s].u[3] = cvt2(r[10], r[11]);
        }

    // ---- bias vectors in C/D row layout (row = (r&3)+8*(r>>2)+4*kh) ----
    f32x16 b2v, b3v0, b3v1;
#pragma unroll
    for (int r = 0; r < 16; ++r) {
        const int n = (r & 3) + 8 * (r >> 2) + 4 * kh;
        b2v[r]  = b2[n];
        b3v0[r] = b3[n];
        b3v1[r] = b3[32 + n];
    }

    f32x16 acc0, acc1;              // pooled relu(h3), rows = neurons, col = c
#pragma unroll
    for (int r = 0; r < 16; ++r) { acc0[r] = 0.f; acc1[r] = 0.f; }

    const int wg = blockIdx.x * 4 + wv;

    // ---- software-pipelined point loads: prefetch pass p+1 during pass p ----
    int p = wg;
    float x0, x1, x2;
    {
        const float* pp = pts + (size_t)(p * 64 + lane) * 3;
        x0 = pp[0]; x1 = pp[1]; x2 = pp[2];
    }
    while (p < npass) {
        const int pnx = p + NWAVES;
        // always-safe prefetch address (falls back to wg's own first batch)
        const float* pn = pts + (size_t)((pnx < npass ? pnx : wg) * 64 + lane) * 3;
        const float n0 = pn[0], n1 = pn[1], n2 = pn[2];   // issued early, used late

        // ---- L1 on VALU (f32 exact) ----
        float h1[16];
#pragma unroll
        for (int j = 0; j < 16; ++j)
            h1[j] = fmaxf(fmaf(x2, W1[3*j+2],
                          fmaf(x1, W1[3*j+1],
                          fmaf(x0, W1[3*j+0], b1[j]))), 0.f);

        const unsigned q0 = cvt2(h1[0],  h1[1]),  q1 = cvt2(h1[2],  h1[3]);
        const unsigned q2 = cvt2(h1[4],  h1[5]),  q3 = cvt2(h1[6],  h1[7]);
        const unsigned q4 = cvt2(h1[8],  h1[9]),  q5 = cvt2(h1[10], h1[11]);
        const unsigned q6 = cvt2(h1[12], h1[13]), q7 = cvt2(h1[14], h1[15]);

        const unsigned s0 = (unsigned)__shfl_xor((int)q0, 32);
        const unsigned s1 = (unsigned)__shfl_xor((int)q1, 32);
        const unsigned s2 = (unsigned)__shfl_xor((int)q2, 32);
        const unsigned s3 = (unsigned)__shfl_xor((int)q3, 32);
        const unsigned s4 = (unsigned)__shfl_xor((int)q4, 32);
        const unsigned s5 = (unsigned)__shfl_xor((int)q5, 32);
        const unsigned s6 = (unsigned)__shfl_xor((int)q6, 32);
        const unsigned s7 = (unsigned)__shfl_xor((int)q7, 32);

        // ---- two point-tiles (cols 0-31 = points p*64+0..31, then +32) ----
#pragma unroll
        for (int ct = 0; ct < 2; ++ct) {
            frag_u bf;                              // B[k][col=point c]
            if (ct == 0) {
                bf.u[0] = kh ? s2 : q0;  bf.u[1] = kh ? s3 : q1;
                bf.u[2] = kh ? s6 : q4;  bf.u[3] = kh ? s7 : q5;
            } else {
                bf.u[0] = kh ? q2 : s0;  bf.u[1] = kh ? q3 : s1;
                bf.u[2] = kh ? q6 : s4;  bf.u[3] = kh ? q7 : s5;
            }

            // L2: D2^T[neuron][point] = W2 x h1^T  (bias in C)
            f32x16 t2 = b2v;
            t2 = __builtin_amdgcn_mfma_f32_32x32x16_bf16(w2f.s8, bf.s8, t2, 0, 0, 0);

            // relu + pack: D-rows ARE the L3 B-frag k-positions
            frag_u pa, pb;                          // k-steps s=0 (n 0-15), s=1 (n 16-31)
#pragma unroll
            for (int e = 0; e < 4; ++e) {
                pa.u[e] = cvt2(fmaxf(t2[2*e],     0.f), fmaxf(t2[2*e + 1],     0.f));
                pb.u[e] = cvt2(fmaxf(t2[8 + 2*e], 0.f), fmaxf(t2[8 + 2*e + 1], 0.f));
            }

            // L3: D3^T[neuron][point] = W3 x relu(h2)^T, 2 n-tiles x 2 k-steps
            f32x16 t3 = b3v0;
            t3 = __builtin_amdgcn_mfma_f32_32x32x16_bf16(w3f[0][0].s8, pa.s8, t3, 0, 0, 0);
            t3 = __builtin_amdgcn_mfma_f32_32x32x16_bf16(w3f[0][1].s8, pb.s8, t3, 0, 0, 0);
#pragma unroll
            for (int r = 0; r < 16; ++r) acc0[r] += fmaxf(t3[r], 0.f);

            f32x16 t4 = b3v1;
            t4 = __builtin_amdgcn_mfma_f32_32x32x16_bf16(w3f[1][0].s8, pa.s8, t4, 0, 0, 0);
            t4 = __builtin_amdgcn_mfma_f32_32x32x16_bf16(w3f[1][1].s8, pb.s8, t4, 0, 0, 0);
#pragma unroll
            for (int r = 0; r < 16; ++r) acc1[r] += fmaxf(t4[r], 0.f);
        }

        x0 = n0; x1 = n1; x2 = n2;     // rotate prefetched batch in
        p = pnx;
    }

    // ---- reduce cols (points) across the 32 lanes of each kh-group ----
#pragma unroll
    for (int r = 0; r < 16; ++r) {
        float a0 = acc0[r], a1 = acc1[r];
        a0 += __shfl_xor(a0, 1);  a1 += __shfl_xor(a1, 1);
        a0 += __shfl_xor(a0, 2);  a1 += __shfl_xor(a1, 2);
        a0 += __shfl_xor(a0, 4);  a1 += __shfl_xor(a1, 4);
        a0 += __shfl_xor(a0, 8);  a1 += __shfl_xor(a1, 8);
        a0 += __shfl_xor(a0, 16); a1 += __shfl_xor(a1, 16);
        if (c == 0) {                       // lanes 0 and 32 (one per kh)
            const int n = (r & 3) + 8 * (r >> 2) + 4 * kh;
            bred[wv][n]      = a0;
            bred[wv][32 + n] = a1;
        }
    }
    __syncthreads();
    if (tid < 64) {
        partialsT[(size_t)tid * GRID1 + blockIdx.x] =
            bred[0][tid] + bred[1][tid] + bred[2][tid] + bred[3][tid];
    }
}

// Fused tail: column-sum partialsT [64][GRID1], mean, apply linear L4.
__global__ __launch_bounds__(256)
void finalize_kernel(const float* __restrict__ partialsT, float inv_n,
                     const float* __restrict__ W4, const float* __restrict__ b4,
                     float* __restrict__ out)
{
    __shared__ float ps[64][4];
    __shared__ float meanv[64];
    const int t = threadIdx.x;          // 256 threads, 1 block
    const int j = t >> 2, q = t & 3;

    float s = 0.f;
    const float* row = partialsT + (size_t)j * GRID1 + q * (GRID1 / 4);
    for (int i = 0; i < GRID1 / 4; ++i) s += row[i];
    ps[j][q] = s;
    __syncthreads();
    if (t < 64) meanv[t] = (ps[t][0] + ps[t][1] + ps[t][2] + ps[t][3]) * inv_n;
    __syncthreads();
    if (t < 128) {
        float s0 = b4[t], s1 = 0.f;
#pragma unroll
        for (int k = 0; k < 64; k += 2) {
            s0 = fmaf(W4[64 * t + k],     meanv[k],     s0);
            s1 = fmaf(W4[64 * t + k + 1], meanv[k + 1], s1);
        }
        out[t] = s0 + s1;
    }
}

extern "C" void kernel_launch(void* const* d_in, const int* in_sizes, int n_in,
                              void* d_out, int out_size, void* d_ws, size_t ws_size,
                              hipStream_t stream)
{
    const float* pts = (const float*)d_in[0];
    const float* W1  = (const float*)d_in[1];
    const float* b1  = (const float*)d_in[2];
    const float* W2  = (const float*)d_in[3];
    const float* b2  = (const float*)d_in[4];
    const float* W3  = (const float*)d_in[5];
    const float* b3  = (const float*)d_in[6];
    const float* W4  = (const float*)d_in[7];
    const float* b4  = (const float*)d_in[8];

    const int npts  = in_sizes[0] / 3;     // 2,000,000
    const int npass = npts / 64;           // 31,250 (exact)
    float* partialsT = (float*)d_ws;       // 64 x GRID1 floats (fully overwritten)

    mlp_mfma2_kernel<<<GRID1, 256, 0, stream>>>(pts, npass, W1, b1, W2, b2, W3, b3, partialsT);
    finalize_kernel<<<1, 256, 0, stream>>>(partialsT, 1.0f / (float)npts, W4, b4, (float*)d_out);
}